// Round 2
// baseline (210.130 us; speedup 1.0000x reference)
//
#include <hip/hip_runtime.h>

#define NUM_FEATURES 64
#define MAX_CAV 5
#define NX 704
#define NY 200
#define NUM_PIXELS (NY * NX)             // 140800
#define TOTAL_PIX (MAX_CAV * NUM_PIXELS) // 704000
#define N_PILLARS 60000
#define X4 (NX / 4)                      // 176
#define C_PER_THREAD 2                   // channels per gather thread

// ---------------------------------------------------------------------------
// Kernel 1: init the pixel->pillar map to -1 (d_ws is re-poisoned to 0xAA
// before every timed launch, so this must run every call). int4 stores.
// ---------------------------------------------------------------------------
__global__ void init_map_kernel(int* __restrict__ map) {
    int i = blockIdx.x * blockDim.x + threadIdx.x;       // index into int4 view
    if (i < TOTAL_PIX / 4) {
        reinterpret_cast<int4*>(map)[i] = make_int4(-1, -1, -1, -1);
    }
}

// ---------------------------------------------------------------------------
// Kernel 2: scatter pillar ids into the map. coords layout: [N, 4] = (b,z,y,x).
// Flat indices are unique by construction (jax permutation), plain stores ok.
// ---------------------------------------------------------------------------
__global__ void scatter_ids_kernel(const int* __restrict__ coords,
                                   int* __restrict__ map) {
    int p = blockIdx.x * blockDim.x + threadIdx.x;
    if (p < N_PILLARS) {
        int b = coords[p * 4 + 0];
        int y = coords[p * 4 + 2];
        int x = coords[p * 4 + 3];
        map[b * NUM_PIXELS + y * NX + x] = p;
    }
}

// ---------------------------------------------------------------------------
// Kernel 3: output-driven gather. One thread produces 4 consecutive x
// positions for C_PER_THREAD channels (one map read, C_PER_THREAD float4
// stores). Every output element is written exactly once -> no separate
// 180 MB zeroing pass. out[b][c][y][x]. Map read as int4 (NX % 4 == 0).
// ---------------------------------------------------------------------------
__global__ void gather_out_kernel(const int* __restrict__ map,
                                  const float* __restrict__ feat,
                                  float* __restrict__ out) {
    const int total_t = MAX_CAV * (NUM_FEATURES / C_PER_THREAD) * NY * X4;
    int t = blockIdx.x * blockDim.x + threadIdx.x;
    if (t >= total_t) return;

    int x4   = t % X4;
    int rest = t / X4;
    int y    = rest % NY;
    rest    /= NY;
    int c0   = (rest % (NUM_FEATURES / C_PER_THREAD)) * C_PER_THREAD;
    int b    = rest / (NUM_FEATURES / C_PER_THREAD);

    int pix4 = b * (NUM_PIXELS / 4) + y * X4 + x4;
    int4 m = reinterpret_cast<const int4*>(map)[pix4];

    // output float4 index for (b, c0, y, x4)
    long long o = ((long long)(b * NUM_FEATURES + c0) * NY + y) * X4 + x4;

    #pragma unroll
    for (int dc = 0; dc < C_PER_THREAD; ++dc) {
        int c = c0 + dc;
        float4 v;
        v.x = (m.x < 0) ? 0.0f : feat[m.x * NUM_FEATURES + c];
        v.y = (m.y < 0) ? 0.0f : feat[m.y * NUM_FEATURES + c];
        v.z = (m.z < 0) ? 0.0f : feat[m.z * NUM_FEATURES + c];
        v.w = (m.w < 0) ? 0.0f : feat[m.w * NUM_FEATURES + c];
        reinterpret_cast<float4*>(out)[o + (long long)dc * (NY * X4)] = v;
    }
}

extern "C" void kernel_launch(void* const* d_in, const int* in_sizes, int n_in,
                              void* d_out, int out_size, void* d_ws, size_t ws_size,
                              hipStream_t stream) {
    const int*   coords = reinterpret_cast<const int*>(d_in[0]);     // [N,4] int32
    const float* feat   = reinterpret_cast<const float*>(d_in[1]);   // [N,64] f32
    float*       out    = reinterpret_cast<float*>(d_out);           // [5,64,200,704]
    int*         map    = reinterpret_cast<int*>(d_ws);              // 704000 ints

    // 1) map <- -1
    {
        int n = TOTAL_PIX / 4;                 // 176000
        int blocks = (n + 255) / 256;
        init_map_kernel<<<blocks, 256, 0, stream>>>(map);
    }
    // 2) map[pixel] <- pillar id
    {
        int blocks = (N_PILLARS + 255) / 256;
        scatter_ids_kernel<<<blocks, 256, 0, stream>>>(coords, map);
    }
    // 3) coalesced gather into output
    {
        int n = MAX_CAV * (NUM_FEATURES / C_PER_THREAD) * NY * X4;  // 5,632,000
        int blocks = (n + 255) / 256;                               // 22000
        gather_out_kernel<<<blocks, 256, 0, stream>>>(map, feat, out);
    }
}

// Round 3
// 199.300 us; speedup vs baseline: 1.0543x; 1.0543x over previous
//
#include <hip/hip_runtime.h>

#define NUM_FEATURES 64
#define MAX_CAV 5
#define NX 704
#define NY 200
#define NUM_PIXELS (NY * NX)             // 140800
#define TOTAL_PIX (MAX_CAV * NUM_PIXELS) // 704000
#define N_PILLARS 60000
#define X4 (NX / 4)                      // 176
#define C_GROUPS 4                       // 64 channels / 16 per thread

// ---------------------------------------------------------------------------
// Kernel 1: init the pixel->pillar map to -1 (d_ws is re-poisoned to 0xAA
// before every timed launch, so this must run every call). int4 stores.
// ---------------------------------------------------------------------------
__global__ void init_map_kernel(int* __restrict__ map) {
    int i = blockIdx.x * blockDim.x + threadIdx.x;       // index into int4 view
    if (i < TOTAL_PIX / 4) {
        reinterpret_cast<int4*>(map)[i] = make_int4(-1, -1, -1, -1);
    }
}

// ---------------------------------------------------------------------------
// Kernel 2: scatter pillar ids into the map. coords layout: [N, 4] = (b,z,y,x).
// Flat indices are unique by construction (jax permutation), plain stores ok.
// ---------------------------------------------------------------------------
__global__ void scatter_ids_kernel(const int* __restrict__ coords,
                                   int* __restrict__ map) {
    int p = blockIdx.x * blockDim.x + threadIdx.x;
    if (p < N_PILLARS) {
        int b = coords[p * 4 + 0];
        int y = coords[p * 4 + 2];
        int x = coords[p * 4 + 3];
        map[b * NUM_PIXELS + y * NX + x] = p;
    }
}

// ---------------------------------------------------------------------------
// Kernel 3: output-driven gather. One thread owns 4 consecutive x positions
// x 16 channels (one 64B feature line per occupied pillar): 1 map int4 read,
// 4x cond float4 feat loads per channel-quad (same cache line across quads),
// 16 float4 coalesced stores. Every output element written exactly once.
// ---------------------------------------------------------------------------
__global__ void gather_out_kernel(const int* __restrict__ map,
                                  const float* __restrict__ feat,
                                  float* __restrict__ out) {
    const int total_t = MAX_CAV * C_GROUPS * NY * X4;    // 704000
    int t = blockIdx.x * blockDim.x + threadIdx.x;
    if (t >= total_t) return;

    int x4   = t % X4;
    int rest = t / X4;
    int y    = rest % NY;
    rest    /= NY;
    int g    = rest % C_GROUPS;          // channel group -> c0 = g*16
    int b    = rest / C_GROUPS;

    int pix4 = b * (NUM_PIXELS / 4) + y * X4 + x4;
    int4 m = reinterpret_cast<const int4*>(map)[pix4];
    int c0 = g * 16;

    // base float4 index into out for (b, c0, y, x4); channel stride in float4s
    size_t obase = ((size_t)(b * NUM_FEATURES + c0) * NY + y) * X4 + x4;
    const size_t cstride = (size_t)NY * X4;              // 35200
    float4* __restrict__ o4 = reinterpret_cast<float4*>(out);

    #pragma unroll
    for (int q = 0; q < 4; ++q) {
        int c = c0 + q * 4;
        const float4 z = make_float4(0.f, 0.f, 0.f, 0.f);
        float4 f0 = z, f1 = z, f2 = z, f3 = z;
        if (m.x >= 0) f0 = *reinterpret_cast<const float4*>(&feat[m.x * NUM_FEATURES + c]);
        if (m.y >= 0) f1 = *reinterpret_cast<const float4*>(&feat[m.y * NUM_FEATURES + c]);
        if (m.z >= 0) f2 = *reinterpret_cast<const float4*>(&feat[m.z * NUM_FEATURES + c]);
        if (m.w >= 0) f3 = *reinterpret_cast<const float4*>(&feat[m.w * NUM_FEATURES + c]);

        // register transpose: channel-major stores over 4 consecutive x
        size_t ob = obase + (size_t)(q * 4) * cstride;
        o4[ob]               = make_float4(f0.x, f1.x, f2.x, f3.x);
        o4[ob + cstride]     = make_float4(f0.y, f1.y, f2.y, f3.y);
        o4[ob + 2 * cstride] = make_float4(f0.z, f1.z, f2.z, f3.z);
        o4[ob + 3 * cstride] = make_float4(f0.w, f1.w, f2.w, f3.w);
    }
}

extern "C" void kernel_launch(void* const* d_in, const int* in_sizes, int n_in,
                              void* d_out, int out_size, void* d_ws, size_t ws_size,
                              hipStream_t stream) {
    const int*   coords = reinterpret_cast<const int*>(d_in[0]);     // [N,4] int32
    const float* feat   = reinterpret_cast<const float*>(d_in[1]);   // [N,64] f32
    float*       out    = reinterpret_cast<float*>(d_out);           // [5,64,200,704]
    int*         map    = reinterpret_cast<int*>(d_ws);              // 704000 ints

    // 1) map <- -1
    {
        int n = TOTAL_PIX / 4;                 // 176000
        int blocks = (n + 255) / 256;
        init_map_kernel<<<blocks, 256, 0, stream>>>(map);
    }
    // 2) map[pixel] <- pillar id
    {
        int blocks = (N_PILLARS + 255) / 256;
        scatter_ids_kernel<<<blocks, 256, 0, stream>>>(coords, map);
    }
    // 3) coalesced gather into output
    {
        int n = MAX_CAV * C_GROUPS * NY * X4;  // 704000
        int blocks = (n + 255) / 256;          // 2750
        gather_out_kernel<<<blocks, 256, 0, stream>>>(map, feat, out);
    }
}